// Round 1
// baseline (545.708 us; speedup 1.0000x reference)
//
#include <hip/hip_runtime.h>

// Problem: B=16, L=4096, D=1024
//   out[b,l,d] = S[b,l,d] + sum_mod outmod[b,d]
//   outmod = ((feat @ Wkv^T + bkv) @ Wv^T + bv) @ Wo^T + bo
//
// Inputs (dict order):
//  0: S [B,L,D]
//  per mod (image din=2048, audio din=1024, text din=768):
//   feat [B,din], Wkv [D,din], bkv [D], Wv [D,D], bv [D], Wo [D,D], bo [D]

#define B_ 16
#define L_ 4096
#define D_ 1024

// One 64-lane wave computes one output element y[b,d] = dot(x[b,:], W[d,:]) + bias[d].
// Lanes stride K with float4 loads (K % 256 == 0 for all stages here).
__global__ void gemv64(const float* __restrict__ x,     // [B, K]
                       const float* __restrict__ W,     // [D, K] row-major
                       const float* __restrict__ bias,  // [D]
                       float* __restrict__ y,           // [B, D]
                       int K, int accumulate) {
    int wave = (blockIdx.x * blockDim.x + threadIdx.x) >> 6;
    int lane = threadIdx.x & 63;
    int b = wave >> 10;          // D = 1024
    int d = wave & 1023;

    const float* xr = x + (size_t)b * K;
    const float* wr = W + (size_t)d * K;

    float sum = 0.f;
    for (int k = lane * 4; k < K; k += 256) {
        float4 xv = *(const float4*)(xr + k);
        float4 wv = *(const float4*)(wr + k);
        sum += xv.x * wv.x + xv.y * wv.y + xv.z * wv.z + xv.w * wv.w;
    }
    // 64-lane butterfly reduction
    for (int off = 32; off; off >>= 1)
        sum += __shfl_xor(sum, off, 64);

    if (lane == 0) {
        float r = sum + bias[d];
        if (accumulate) y[wave] += r;
        else            y[wave]  = r;
    }
}

// out[b,l,d] = S[b,l,d] + delta[b,d]; one float4 per thread.
// float4 flat index i: b = i >> 20 (L*D/4 = 2^20), d4 = i & 255 (D/4 = 256).
__global__ void add_bcast(const float4* __restrict__ S,
                          const float4* __restrict__ delta,  // [B, D/4]
                          float4* __restrict__ out) {
    int i = blockIdx.x * blockDim.x + threadIdx.x;
    int b  = i >> 20;
    int d4 = i & 255;
    float4 s = S[i];
    float4 dl = delta[(b << 8) + d4];
    float4 r;
    r.x = s.x + dl.x;
    r.y = s.y + dl.y;
    r.z = s.z + dl.z;
    r.w = s.w + dl.w;
    out[i] = r;
}

extern "C" void kernel_launch(void* const* d_in, const int* in_sizes, int n_in,
                              void* d_out, int out_size, void* d_ws, size_t ws_size,
                              hipStream_t stream) {
    const float* S = (const float*)d_in[0];

    // Per-modality input pointers
    const int dins[3] = {2048, 1024, 768};
    const float *feat[3], *Wkv[3], *bkv[3], *Wv[3], *bv[3], *Wo[3], *bo[3];
    for (int m = 0; m < 3; ++m) {
        int base = 1 + m * 7;
        feat[m] = (const float*)d_in[base + 0];
        Wkv[m]  = (const float*)d_in[base + 1];
        bkv[m]  = (const float*)d_in[base + 2];
        Wv[m]   = (const float*)d_in[base + 3];
        bv[m]   = (const float*)d_in[base + 4];
        Wo[m]   = (const float*)d_in[base + 5];
        bo[m]   = (const float*)d_in[base + 6];
    }

    // Workspace layout (floats): kv[3][B*D], v[3][B*D], delta[B*D]
    float* ws = (float*)d_ws;
    const int BD = B_ * D_;
    float* kv[3]  = {ws, ws + BD, ws + 2 * BD};
    float* v[3]   = {ws + 3 * BD, ws + 4 * BD, ws + 5 * BD};
    float* delta  = ws + 6 * BD;

    const int gemv_blocks = (BD * 64) / 256;   // 1 wave per output elem, 4 waves/block
    const dim3 gb(gemv_blocks), tb(256);

    // Stage 1: kv = feat @ Wkv^T + bkv
    for (int m = 0; m < 3; ++m)
        gemv64<<<gb, tb, 0, stream>>>(feat[m], Wkv[m], bkv[m], kv[m], dins[m], 0);
    // Stage 2: v = kv @ Wv^T + bv
    for (int m = 0; m < 3; ++m)
        gemv64<<<gb, tb, 0, stream>>>(kv[m], Wv[m], bv[m], v[m], D_, 0);
    // Stage 3: delta = sum_m (v @ Wo^T + bo)
    for (int m = 0; m < 3; ++m)
        gemv64<<<gb, tb, 0, stream>>>(v[m], Wo[m], bo[m], delta, D_, m != 0);

    // Broadcast add over [B, L, D]
    const int total4 = (B_ * L_ * D_) / 4;     // 16,777,216 float4s
    add_bcast<<<total4 / 256, 256, 0, stream>>>((const float4*)S,
                                                (const float4*)delta,
                                                (float4*)d_out);
}

// Round 2
// 533.614 us; speedup vs baseline: 1.0227x; 1.0227x over previous
//
#include <hip/hip_runtime.h>

// Problem: B=16, L=4096, D=1024
//   out[b,l,d] = S[b,l,d] + sum_mod outmod[b,d]
//   outmod = ((feat @ Wkv^T + bkv) @ Wv^T + bv) @ Wo^T + bo
// dins: image=2048, audio=1024, text=768

#define B_ 16
#define L_ 4096
#define D_ 1024

typedef float v4f __attribute__((ext_vector_type(4)));

struct StageArgs {
    const float* x[3];   // [B, K[m]]
    const float* W[3];   // [D, K[m]]
    const float* bias[3];// [D]
    float*       y[3];   // [B, D]
    int          K[3];
};

// Fused across modalities: 3 * 16384 waves, one wave per (m, b, d) dot.
// wid>>14 = m ; (wid>>10)&15 = b ; wid&1023 = d
__global__ __launch_bounds__(256) void gemv_stage(StageArgs a) {
    int wid  = (blockIdx.x * 256 + threadIdx.x) >> 6;
    int lane = threadIdx.x & 63;
    int m = wid >> 14;
    int r = wid & 16383;
    int bb = r >> 10;
    int d  = r & 1023;
    int K = a.K[m];

    const float* xr = a.x[m] + bb * K;
    const float* wr = a.W[m] + (size_t)d * K;

    float sum = 0.f;
    for (int k = lane * 4; k < K; k += 256) {
        float4 xv = *(const float4*)(xr + k);
        float4 wv = *(const float4*)(wr + k);
        sum += xv.x * wv.x + xv.y * wv.y + xv.z * wv.z + xv.w * wv.w;
    }
    for (int off = 32; off; off >>= 1) sum += __shfl_xor(sum, off, 64);

    if (lane == 0) a.y[m][(bb << 10) + d] = sum + a.bias[m][d];
}

struct Stage3Args {
    const float* v0; const float* v1; const float* v2;   // [B, D] each
    const float* W0; const float* W1; const float* W2;   // [D, D] each
    const float* b0; const float* b1; const float* b2;   // [D]
    float* delta;                                        // [B, D]
};

// 16384 waves; one wave computes delta[b,d] = sum_m dot(v_m[b,:], Wo_m[d,:]) + biases
__global__ __launch_bounds__(256) void gemv_stage3(Stage3Args a) {
    int wid  = (blockIdx.x * 256 + threadIdx.x) >> 6;
    int lane = threadIdx.x & 63;
    int bb = wid >> 10;
    int d  = wid & 1023;

    const float* xs[3] = { a.v0 + (bb << 10), a.v1 + (bb << 10), a.v2 + (bb << 10) };
    const float* ws[3] = { a.W0 + ((size_t)d << 10), a.W1 + ((size_t)d << 10),
                           a.W2 + ((size_t)d << 10) };
    float sum = 0.f;
    #pragma unroll
    for (int m = 0; m < 3; ++m) {
        const float* xr = xs[m];
        const float* wr = ws[m];
        #pragma unroll
        for (int k = lane * 4; k < 1024; k += 256) {
            float4 xv = *(const float4*)(xr + k);
            float4 wv = *(const float4*)(wr + k);
            sum += xv.x * wv.x + xv.y * wv.y + xv.z * wv.z + xv.w * wv.w;
        }
    }
    for (int off = 32; off; off >>= 1) sum += __shfl_xor(sum, off, 64);

    if (lane == 0)
        a.delta[(bb << 10) + d] = sum + a.b0[d] + a.b1[d] + a.b2[d];
}

// out[b,l,d] = S[b,l,d] + delta[b,d]; grid-stride, nontemporal streaming.
// float4 flat index i: b = i >> 20, d4 = i & 255.
__global__ __launch_bounds__(256) void add_bcast(const v4f* __restrict__ S,
                                                 const v4f* __restrict__ delta,
                                                 v4f* __restrict__ out, int total4) {
    int stride = gridDim.x * 256;
    for (int i = blockIdx.x * 256 + threadIdx.x; i < total4; i += stride) {
        int b  = i >> 20;
        int d4 = i & 255;
        v4f s  = __builtin_nontemporal_load(S + i);
        v4f dl = delta[(b << 8) + d4];
        __builtin_nontemporal_store(s + dl, out + i);
    }
}

extern "C" void kernel_launch(void* const* d_in, const int* in_sizes, int n_in,
                              void* d_out, int out_size, void* d_ws, size_t ws_size,
                              hipStream_t stream) {
    const float* S = (const float*)d_in[0];

    const int dins[3] = {2048, 1024, 768};
    const float *feat[3], *Wkv[3], *bkv[3], *Wv[3], *bv[3], *Wo[3], *bo[3];
    for (int m = 0; m < 3; ++m) {
        int base = 1 + m * 7;
        feat[m] = (const float*)d_in[base + 0];
        Wkv[m]  = (const float*)d_in[base + 1];
        bkv[m]  = (const float*)d_in[base + 2];
        Wv[m]   = (const float*)d_in[base + 3];
        bv[m]   = (const float*)d_in[base + 4];
        Wo[m]   = (const float*)d_in[base + 5];
        bo[m]   = (const float*)d_in[base + 6];
    }

    float* ws = (float*)d_ws;
    const int BD = B_ * D_;
    float* kv[3]  = {ws, ws + BD, ws + 2 * BD};
    float* v[3]   = {ws + 3 * BD, ws + 4 * BD, ws + 5 * BD};
    float* delta  = ws + 6 * BD;

    // Stage 1: kv[m] = feat[m] @ Wkv[m]^T + bkv[m]   (3*16384 waves)
    StageArgs s1;
    for (int m = 0; m < 3; ++m) {
        s1.x[m] = feat[m]; s1.W[m] = Wkv[m]; s1.bias[m] = bkv[m];
        s1.y[m] = kv[m];   s1.K[m] = dins[m];
    }
    gemv_stage<<<12288, 256, 0, stream>>>(s1);

    // Stage 2: v[m] = kv[m] @ Wv[m]^T + bv[m]
    StageArgs s2;
    for (int m = 0; m < 3; ++m) {
        s2.x[m] = kv[m]; s2.W[m] = Wv[m]; s2.bias[m] = bv[m];
        s2.y[m] = v[m];  s2.K[m] = D_;
    }
    gemv_stage<<<12288, 256, 0, stream>>>(s2);

    // Stage 3: delta = sum_m (v[m] @ Wo[m]^T + bo[m])   (16384 waves)
    Stage3Args s3 = { v[0], v[1], v[2], Wo[0], Wo[1], Wo[2], bo[0], bo[1], bo[2], delta };
    gemv_stage3<<<4096, 256, 0, stream>>>(s3);

    // Broadcast add: 16,777,216 float4s, 4 per thread
    const int total4 = (B_ * L_ * D_) / 4;
    add_bcast<<<16384, 256, 0, stream>>>((const v4f*)S, (const v4f*)delta,
                                         (v4f*)d_out, total4);
}